// Round 4
// baseline (533.553 us; speedup 1.0000x reference)
//
#include <hip/hip_runtime.h>
#include <hip/hip_bf16.h>

#define C 128
#define L 16384
#define B 8
#define MID 32
#define NBL (B * L)

typedef unsigned short ushort_t;
typedef __attribute__((ext_vector_type(8))) short s8v;   // 8 bf16
typedef __attribute__((ext_vector_type(4))) float f4v;   // 4 fp32

__device__ __forceinline__ unsigned short f2bf(float f) {
    union { float f; unsigned int u; } a; a.f = f;
    unsigned int u = a.u;
    return (unsigned short)((u + 0x7fffu + ((u >> 16) & 1u)) >> 16);
}

__device__ __forceinline__ void load8(const ushort_t* p, float* f) {
    uint4 u = *(const uint4*)p;
    f[0] = __uint_as_float(u.x << 16); f[1] = __uint_as_float(u.x & 0xffff0000u);
    f[2] = __uint_as_float(u.y << 16); f[3] = __uint_as_float(u.y & 0xffff0000u);
    f[4] = __uint_as_float(u.z << 16); f[5] = __uint_as_float(u.z & 0xffff0000u);
    f[6] = __uint_as_float(u.w << 16); f[7] = __uint_as_float(u.w & 0xffff0000u);
}

__device__ __forceinline__ void zero8(float* f) {
#pragma unroll
    for (int j = 0; j < 8; j++) f[j] = 0.f;
}

__device__ __forceinline__ void store8_lds(ushort_t* p, const float* f) {
    union { ushort_t h[8]; uint4 q; } u;
#pragma unroll
    for (int j = 0; j < 8; j++) u.h[j] = f2bf(f[j]);
    *(uint4*)p = u.q;
}

__device__ __forceinline__ void ld8f(const float* p, float* f) {
    float4 a = *(const float4*)p;
    float4 b = *(const float4*)(p + 4);
    f[0] = a.x; f[1] = a.y; f[2] = a.z; f[3] = a.w;
    f[4] = b.x; f[5] = b.y; f[6] = b.z; f[7] = b.w;
}

// ------------------------------------------------ k_cvt: x fp32 [b][c][l] -> xb bf16 [b][l][c], + gap sums
__global__ __launch_bounds__(256) void k_cvt(const float* __restrict__ x,
                                             ushort_t* __restrict__ xb,
                                             float* __restrict__ gap) {
    __shared__ float xs[64][129];
    const int bid = blockIdx.x;
    const int b = bid >> 8;
    const int l0 = (bid & 255) * 64;
    const int tid = threadIdx.x;
    const int c = tid >> 1, h = tid & 1;
    const float* src = x + ((size_t)(b * C + c)) * L + l0 + h * 32;
    float s = 0.f;
#pragma unroll
    for (int j = 0; j < 8; j++) {
        float4 v = *(const float4*)(src + j * 4);
        s += (v.x + v.y) + (v.z + v.w);
        int lb = h * 32 + j * 4;
        xs[lb + 0][c] = v.x; xs[lb + 1][c] = v.y;
        xs[lb + 2][c] = v.z; xs[lb + 3][c] = v.w;
    }
    s += __shfl_xor(s, 1);
    if (h == 0) atomicAdd(&gap[b * C + c], s);
    __syncthreads();
    const int l = tid & 63, quarter = tid >> 6, cb = quarter * 32;
    union { ushort_t hh[32]; uint4 q[4]; } u;
#pragma unroll
    for (int k = 0; k < 32; k++) u.hh[k] = f2bf(xs[l][cb + k]);
    uint4* dst = (uint4*)(xb + ((size_t)(b * L + l0 + l)) * C + cb);
#pragma unroll
    for (int k = 0; k < 4; k++) dst[k] = u.q[k];
}

// ------------------------------------------------ k_prep_b
__global__ __launch_bounds__(128) void k_prep_b(const float* __restrict__ gap,
                                                const float* __restrict__ w1,
                                                const float* __restrict__ Wco,
                                                float* __restrict__ a,
                                                float* __restrict__ gw) {
    int b = blockIdx.x, c = threadIdx.x;
    __shared__ float gl[C];
    __shared__ float red[C];
    float v = gap[b * C + c] * (1.f / (float)L);
    red[c] = v * v;
    __syncthreads();
    for (int w = 64; w > 0; w >>= 1) {
        if (c < w) red[c] += red[c + w];
        __syncthreads();
    }
    float nrm = fmaxf(sqrtf(red[0]), 1e-12f);
    float gc = v / nrm;
    gl[c] = gc;
    __syncthreads();
    if (c < MID) {
        float s = 0.f;
        for (int k = 0; k < C; k++) s = fmaf(w1[c * C + k], gl[k], s);
        a[b * MID + c] = s;
    }
    {
        float s = 0.f;
        for (int k = 0; k < C; k++) s = fmaf(gl[k], Wco[k * C + c], s);
        gw[b * C + c] = s;
    }
}

// ------------------------------------------------ k_prep_w
__global__ __launch_bounds__(128) void k_prep_w(const float* __restrict__ Win,
                                                const float* __restrict__ Wci,
                                                const float* __restrict__ Wproj,
                                                const float* __restrict__ Wout,
                                                const float* __restrict__ w2,
                                                const float* __restrict__ b2,
                                                const float* __restrict__ wds,
                                                const float* __restrict__ wcd,
                                                ushort_t* __restrict__ Wio,
                                                ushort_t* __restrict__ Wcat,
                                                float* __restrict__ bp,
                                                float* __restrict__ kwS,
                                                float* __restrict__ kw1,
                                                float* __restrict__ kd0,
                                                float* __restrict__ kd1,
                                                float* __restrict__ kd2) {
    int o = blockIdx.x, c = threadIdx.x;
    __shared__ float pr[C];
    pr[c] = Wproj[o * C + c];
    __syncthreads();
    Wio[o * C + c] = f2bf(Win[o * C + c]);
    Wio[(C + o) * C + c] = f2bf(Wci[o * C + c]);
    float s = 0.f;
    for (int k = 0; k < C; k++) s = fmaf(pr[k], Wout[k * C + c], s);
    Wcat[o * 288 + c] = f2bf(s);
    Wcat[o * 288 + 128 + c] = f2bf(pr[c]);
    if (c < MID) {
        float s2 = 0.f;
        for (int k = 0; k < C; k++) s2 = fmaf(pr[k], w2[k * MID + c], s2);
        Wcat[o * 288 + 256 + c] = f2bf(s2);
    }
    if (c == 0) {
        float s3 = 0.f;
        for (int k = 0; k < C; k++) s3 = fmaf(pr[k], b2[k], s3);
        bp[o] = s3;
    }
    if (o == 0) {
        kwS[c] = 0.25f * (wds[3 * c] + wds[3 * c + 2]);
        kw1[c] = wds[3 * c + 1];
        kd0[c] = wcd[3 * c];
        kd1[c] = wcd[3 * c + 1];
        kd2[c] = wcd[3 * c + 2];
    }
}

// ------------------------------------------------ k_gemm1: tu[l][0:256] = [Win;Wci] @ x  (MFMA)
__global__ __launch_bounds__(512, 1) void k_gemm1(const ushort_t* __restrict__ xb,
                                                  const ushort_t* __restrict__ Wio,
                                                  ushort_t* __restrict__ tu) {
    __shared__ ushort_t wl[128 * 136];
    const int tid = threadIdx.x;
    const int bid = blockIdx.x;               // 8 b * 2 ms * 128 lt
    const int b = bid >> 8;
    const int ms = (bid >> 7) & 1;
    const int lt = bid & 127;
    {
        int row = tid >> 2, qq = tid & 3;
        const uint4* s4 = (const uint4*)(Wio + (ms * C + row) * C + qq * 32);
        uint4* d4 = (uint4*)(wl + row * 136 + qq * 32);
        d4[0] = s4[0]; d4[1] = s4[1]; d4[2] = s4[2]; d4[3] = s4[3];
    }
    __syncthreads();
    const int wave = tid >> 6, lane = tid & 63;
    const int l0 = lt * 128 + wave * 16;
    const int n = lane & 15, q = lane >> 4;
    const ushort_t* brow = xb + ((size_t)(b * L + l0 + n)) * C + q * 8;
    s8v bfrag[4];
#pragma unroll
    for (int ks = 0; ks < 4; ks++) bfrag[ks] = *(const s8v*)(brow + ks * 32);
    f4v acc[8];
#pragma unroll
    for (int i = 0; i < 8; i++) acc[i] = (f4v){0.f, 0.f, 0.f, 0.f};
#pragma unroll
    for (int ks = 0; ks < 4; ks++) {
#pragma unroll
        for (int mt = 0; mt < 8; mt++) {
            s8v af = *(const s8v*)(wl + (mt * 16 + n) * 136 + ks * 32 + q * 8);
            acc[mt] = __builtin_amdgcn_mfma_f32_16x16x32_bf16(af, bfrag[ks], acc[mt], 0, 0, 0);
        }
    }
    ushort_t* orow = tu + ((size_t)(b * L + l0 + n)) * 256 + ms * C + q * 4;
#pragma unroll
    for (int mt = 0; mt < 8; mt++) {
        union { ushort_t h[4]; uint2 q2; } u;
#pragma unroll
        for (int i = 0; i < 4; i++) u.h[i] = f2bf(acc[mt][i]);
        *(uint2*)(orow + mt * 16) = u.q2;
    }
}

// ------------------------------------------------ k_fuse2: stencils -> LDS Kb tile -> MFMA out + BN stats
__global__ __launch_bounds__(256, 4) void k_fuse2(
    const ushort_t* __restrict__ tu, const ushort_t* __restrict__ xb,
    const float* __restrict__ kwS, const float* __restrict__ kw1,
    const float* __restrict__ kd0, const float* __restrict__ kd1,
    const float* __restrict__ kd2, const float* __restrict__ gw,
    const float* __restrict__ a, const float* __restrict__ b1,
    const float* __restrict__ pdw, const ushort_t* __restrict__ Wcat,
    const float* __restrict__ bp, float* __restrict__ outp,
    float* __restrict__ stats) {
    __shared__ ushort_t Kl[64 * 296];                 // 37,888 B
    const int tid = threadIdx.x;
    const int bid = blockIdx.x;                        // 2048: b * 256 tiles
    const int b = bid >> 8;
    const int l0 = (bid & 255) * 64;
    const size_t rb = (size_t)b * L;
    const int cc = tid & 15, p16 = tid >> 4;
    const int c0 = cc * 8;

    // constants per cc (invariant over st)
    float kS[8], k1[8], d0[8], d1[8], d2[8], gv[8];
    ld8f(kwS + c0, kS); ld8f(kw1 + c0, k1);
    ld8f(kd0 + c0, d0); ld8f(kd1 + c0, d1); ld8f(kd2 + c0, d2);
    ld8f(gw + b * C + c0, gv);
    const float dwt = pdw[0] * 0.25f;
    float av[8], bv[8];
    if (cc < 4) { ld8f(a + b * MID + cc * 8, av); ld8f(b1 + cc * 8, bv); }

    // -------- phase 1: stencil tile into LDS
    for (int st = 0; st < 4; st++) {
        const int p = st * 16 + p16;
        const int l = l0 + p;
        const int y = l >> 7, xg = l & 127;

        const int rL = (l > 0) ? (l - 1) : -1;
        const int rR = (l < L - 1) ? (l + 1) : -1;
        const int rU = (y > 0) ? (l - 128) : ((xg > 0) ? (16256 + xg - 1) : -1);
        const int rD = (y < 127) ? (l + 128) : ((xg < 127) ? (xg + 1) : -1);
        const int sL = (xg > 0) ? (l - 1) : (l + 1);
        const int sR = (xg < 127) ? (l + 1) : (l - 1);
        const int sU = (y > 0) ? (l - 128) : (l + 128);
        const int sD = (y < 127) ? (l + 128) : (l - 128);

        float tC[8], tLe[8], tRi[8], tUp[8], tDo[8];
        load8(tu + (rb + l) * 256 + c0, tC);
        if (rL >= 0) load8(tu + (rb + rL) * 256 + c0, tLe); else zero8(tLe);
        if (rR >= 0) load8(tu + (rb + rR) * 256 + c0, tRi); else zero8(tRi);
        if (rU >= 0) load8(tu + (rb + rU) * 256 + c0, tUp); else zero8(tUp);
        if (rD >= 0) load8(tu + (rb + rD) * 256 + c0, tDo); else zero8(tDo);

        float uC[8], uL8[8], uR8[8];
        load8(tu + (rb + l) * 256 + 128 + c0, uC);
        if (rL >= 0) load8(tu + (rb + rL) * 256 + 128 + c0, uL8); else zero8(uL8);
        if (rR >= 0) load8(tu + (rb + rR) * 256 + 128 + c0, uR8); else zero8(uR8);

        float xC[8], xL8[8], xR8[8], xU8[8], xD8[8];
        load8(xb + (rb + l) * C + c0, xC);
        load8(xb + (rb + sL) * C + c0, xL8);
        load8(xb + (rb + sR) * C + c0, xR8);
        load8(xb + (rb + sU) * C + c0, xU8);
        load8(xb + (rb + sD) * C + c0, xD8);

        float ct[8], yd[8];
        float s1 = 0.f;
#pragma unroll
        for (int j = 0; j < 8; j++) {
            ct[j] = kS[j] * ((tLe[j] + tRi[j]) + (tUp[j] + tDo[j])) + k1[j] * tC[j];
            float vv = d0[j] * uL8[j] + d1[j] * uC[j] + d2[j] * uR8[j];
            s1 = fmaf(gv[j], vv, s1);
            float cen = xC[j];
            float d = fabsf(cen - xL8[j]) + fabsf(cen - xR8[j]) +
                      fabsf(cen - xU8[j]) + fabsf(cen - xD8[j]);
            yd[j] = fmaf(dwt, d, cen);
        }
        s1 += __shfl_xor(s1, 1);
        s1 += __shfl_xor(s1, 2);
        s1 += __shfl_xor(s1, 4);
        s1 += __shfl_xor(s1, 8);

        ushort_t* kr = Kl + p * 296;
        store8_lds(kr + c0, ct);
        store8_lds(kr + 128 + c0, yd);
        if (cc < 4) {
            float sv[8];
#pragma unroll
            for (int j = 0; j < 8; j++) {
                float pre = fmaf(av[j], s1, bv[j]);
                sv[j] = pre / (1.f + __expf(-pre));
            }
            store8_lds(kr + 256 + cc * 8, sv);
        }
    }
    __syncthreads();

    // -------- phase 2: MFMA. wave w owns M-rows (w*2+mtl)*16, all 4 pos-subtiles
    const int w = tid >> 6, lane = tid & 63;
    const int n = lane & 15, q = lane >> 4;
    f4v acc[2][4];
#pragma unroll
    for (int m = 0; m < 2; m++)
#pragma unroll
        for (int t = 0; t < 4; t++) acc[m][t] = (f4v){0.f, 0.f, 0.f, 0.f};
    const ushort_t* A0 = Wcat + ((w * 2 + 0) * 16 + n) * 288 + q * 8;
    const ushort_t* A1 = Wcat + ((w * 2 + 1) * 16 + n) * 288 + q * 8;
#pragma unroll
    for (int ks = 0; ks < 9; ks++) {
        s8v a0 = *(const s8v*)(A0 + ks * 32);
        s8v a1 = *(const s8v*)(A1 + ks * 32);
#pragma unroll
        for (int t = 0; t < 4; t++) {
            s8v bf_ = *(const s8v*)(Kl + (t * 16 + n) * 296 + ks * 32 + q * 8);
            acc[0][t] = __builtin_amdgcn_mfma_f32_16x16x32_bf16(a0, bf_, acc[0][t], 0, 0, 0);
            acc[1][t] = __builtin_amdgcn_mfma_f32_16x16x32_bf16(a1, bf_, acc[1][t], 0, 0, 0);
        }
    }

    // -------- phase 3: bias + store + BN partial stats
#pragma unroll
    for (int mtl = 0; mtl < 2; mtl++) {
        const int o0 = (w * 2 + mtl) * 16 + q * 4;
        float4 bpv = *(const float4*)(bp + o0);
        float ba[4] = {bpv.x, bpv.y, bpv.z, bpv.w};
#pragma unroll
        for (int i = 0; i < 4; i++) {
            const int o = o0 + i;
            float s = 0.f, sq = 0.f;
#pragma unroll
            for (int t = 0; t < 4; t++) {
                float v = acc[mtl][t][i] + ba[i];
                outp[((size_t)(b * C + o)) * L + l0 + t * 16 + n] = v;
                s += v;
                sq = fmaf(v, v, sq);
            }
            s += __shfl_xor(s, 1); s += __shfl_xor(s, 2);
            s += __shfl_xor(s, 4); s += __shfl_xor(s, 8);
            sq += __shfl_xor(sq, 1); sq += __shfl_xor(sq, 2);
            sq += __shfl_xor(sq, 4); sq += __shfl_xor(sq, 8);
            if (n == 0) {
                atomicAdd(&stats[o], s);
                atomicAdd(&stats[C + o], sq);
            }
        }
    }
}

// ------------------------------------------------ BN finalize + apply
__global__ void k_bnfin(const float* __restrict__ stats, const float* __restrict__ gamma,
                        const float* __restrict__ beta, float* __restrict__ scsh) {
    int o = threadIdx.x;
    float n = (float)NBL;
    float mu = stats[o] / n;
    float var = stats[C + o] / n - mu * mu;
    float sc = gamma[o] * rsqrtf(var + 1e-5f);
    scsh[o] = sc;
    scsh[C + o] = fmaf(-mu, sc, beta[o]);
}

__global__ __launch_bounds__(256) void k_bnapply(float* __restrict__ outp,
                                                 const float* __restrict__ scsh) {
    int bid = blockIdx.x;             // 2048
    int bo = bid >> 1;
    int half = bid & 1;
    int o = bo & (C - 1);
    float sc = scsh[o], sh = scsh[C + o];
    float4* p = (float4*)(outp + (size_t)bo * L + half * (L / 2));
    for (int i = threadIdx.x; i < L / 8; i += 256) {
        float4 v = p[i];
        v.x = fmaf(v.x, sc, sh);
        v.y = fmaf(v.y, sc, sh);
        v.z = fmaf(v.z, sc, sh);
        v.w = fmaf(v.w, sc, sh);
        p[i] = v;
    }
}

// ------------------------------------------------ launch
extern "C" void kernel_launch(void* const* d_in, const int* in_sizes, int n_in,
                              void* d_out, int out_size, void* d_ws, size_t ws_size,
                              hipStream_t stream) {
    const float* x = (const float*)d_in[0];
    const float* Win = (const float*)d_in[1];
    const float* wds = (const float*)d_in[2];
    const float* Wout = (const float*)d_in[3];
    const float* Wci = (const float*)d_in[4];
    const float* wcd = (const float*)d_in[5];
    const float* Wco = (const float*)d_in[6];
    const float* w1 = (const float*)d_in[7];
    const float* b1 = (const float*)d_in[8];
    const float* w2 = (const float*)d_in[9];
    const float* b2 = (const float*)d_in[10];
    const float* pdw = (const float*)d_in[11];
    const float* gamma = (const float*)d_in[12];
    const float* beta = (const float*)d_in[13];
    const float* Wproj = (const float*)d_in[14];

    char* wsb = (char*)d_ws;
    ushort_t* xb = (ushort_t*)wsb;                       // 33,554,432 B
    ushort_t* tu = (ushort_t*)(wsb + 33554432);          // 67,108,864 B
    char* S = wsb + 100663296;
    float* gap  = (float*)(S + 0);        // 1024 fl
    float* stats= (float*)(S + 4096);     // 256 fl
    float* scsh = (float*)(S + 5120);     // 256 fl
    float* a    = (float*)(S + 6144);     // 256 fl
    float* gw   = (float*)(S + 7168);     // 1024 fl
    float* bp   = (float*)(S + 11264);    // 128 fl
    float* kwS  = (float*)(S + 11776);
    float* kw1  = (float*)(S + 12288);
    float* kd0  = (float*)(S + 12800);
    float* kd1  = (float*)(S + 13312);
    float* kd2  = (float*)(S + 13824);
    ushort_t* Wio  = (ushort_t*)(S + 14336);   // 65,536 B
    ushort_t* Wcat = (ushort_t*)(S + 79872);   // 73,728 B
    float* outp = (float*)d_out;

    hipMemsetAsync(S, 0, 5120, stream);  // gap + stats
    k_cvt<<<2048, 256, 0, stream>>>(x, xb, gap);
    k_prep_b<<<8, 128, 0, stream>>>(gap, w1, Wco, a, gw);
    k_prep_w<<<128, 128, 0, stream>>>(Win, Wci, Wproj, Wout, w2, b2, wds, wcd,
                                      Wio, Wcat, bp, kwS, kw1, kd0, kd1, kd2);
    k_gemm1<<<2048, 512, 0, stream>>>(xb, Wio, tu);
    k_fuse2<<<2048, 256, 0, stream>>>(tu, xb, kwS, kw1, kd0, kd1, kd2, gw, a, b1,
                                      pdw, Wcat, bp, outp, stats);
    k_bnfin<<<1, 128, 0, stream>>>(stats, gamma, beta, scsh);
    k_bnapply<<<2048, 256, 0, stream>>>(outp, scsh);
}

// Round 5
// 315.122 us; speedup vs baseline: 1.6932x; 1.6932x over previous
//
#include <hip/hip_runtime.h>
#include <hip/hip_bf16.h>

#define C 128
#define L 16384
#define B 8
#define MID 32
#define NBL (B * L)

typedef unsigned short ushort_t;
typedef __attribute__((ext_vector_type(8))) short s8v;   // 8 bf16
typedef __attribute__((ext_vector_type(4))) float f4v;   // 4 fp32

__device__ __forceinline__ unsigned short f2bf(float f) {
    union { float f; unsigned int u; } a; a.f = f;
    unsigned int u = a.u;
    return (unsigned short)((u + 0x7fffu + ((u >> 16) & 1u)) >> 16);
}

__device__ __forceinline__ void load8(const ushort_t* p, float* f) {
    uint4 u = *(const uint4*)p;
    f[0] = __uint_as_float(u.x << 16); f[1] = __uint_as_float(u.x & 0xffff0000u);
    f[2] = __uint_as_float(u.y << 16); f[3] = __uint_as_float(u.y & 0xffff0000u);
    f[4] = __uint_as_float(u.z << 16); f[5] = __uint_as_float(u.z & 0xffff0000u);
    f[6] = __uint_as_float(u.w << 16); f[7] = __uint_as_float(u.w & 0xffff0000u);
}

__device__ __forceinline__ void zero8(float* f) {
#pragma unroll
    for (int j = 0; j < 8; j++) f[j] = 0.f;
}

__device__ __forceinline__ void store8(ushort_t* p, const float* f) {
    union { ushort_t h[8]; uint4 q; } u;
#pragma unroll
    for (int j = 0; j < 8; j++) u.h[j] = f2bf(f[j]);
    *(uint4*)p = u.q;
}

__device__ __forceinline__ void ld8f(const float* p, float* f) {
    float4 a = *(const float4*)p;
    float4 b = *(const float4*)(p + 4);
    f[0] = a.x; f[1] = a.y; f[2] = a.z; f[3] = a.w;
    f[4] = b.x; f[5] = b.y; f[6] = b.z; f[7] = b.w;
}

// ------------------------------------------------ k_cvt: x fp32 [b][c][l] -> xb bf16 [b][l][c], + gap sums
__global__ __launch_bounds__(256) void k_cvt(const float* __restrict__ x,
                                             ushort_t* __restrict__ xb,
                                             float* __restrict__ gap) {
    __shared__ float xs[64][129];
    const int bid = blockIdx.x;
    const int b = bid >> 8;
    const int l0 = (bid & 255) * 64;
    const int tid = threadIdx.x;
    const int c = tid >> 1, h = tid & 1;
    const float* src = x + ((size_t)(b * C + c)) * L + l0 + h * 32;
    float s = 0.f;
#pragma unroll
    for (int j = 0; j < 8; j++) {
        float4 v = *(const float4*)(src + j * 4);
        s += (v.x + v.y) + (v.z + v.w);
        int lb = h * 32 + j * 4;
        xs[lb + 0][c] = v.x; xs[lb + 1][c] = v.y;
        xs[lb + 2][c] = v.z; xs[lb + 3][c] = v.w;
    }
    s += __shfl_xor(s, 1);
    if (h == 0) atomicAdd(&gap[b * C + c], s);
    __syncthreads();
    const int l = tid & 63, quarter = tid >> 6, cb = quarter * 32;
    union { ushort_t hh[32]; uint4 q[4]; } u;
#pragma unroll
    for (int k = 0; k < 32; k++) u.hh[k] = f2bf(xs[l][cb + k]);
    uint4* dst = (uint4*)(xb + ((size_t)(b * L + l0 + l)) * C + cb);
#pragma unroll
    for (int k = 0; k < 4; k++) dst[k] = u.q[k];
}

// ------------------------------------------------ k_prep_b
__global__ __launch_bounds__(128) void k_prep_b(const float* __restrict__ gap,
                                                const float* __restrict__ w1,
                                                const float* __restrict__ Wco,
                                                float* __restrict__ a,
                                                float* __restrict__ gw) {
    int b = blockIdx.x, c = threadIdx.x;
    __shared__ float gl[C];
    __shared__ float red[C];
    float v = gap[b * C + c] * (1.f / (float)L);
    red[c] = v * v;
    __syncthreads();
    for (int w = 64; w > 0; w >>= 1) {
        if (c < w) red[c] += red[c + w];
        __syncthreads();
    }
    float nrm = fmaxf(sqrtf(red[0]), 1e-12f);
    float gc = v / nrm;
    gl[c] = gc;
    __syncthreads();
    if (c < MID) {
        float s = 0.f;
        for (int k = 0; k < C; k++) s = fmaf(w1[c * C + k], gl[k], s);
        a[b * MID + c] = s;
    }
    {
        float s = 0.f;
        for (int k = 0; k < C; k++) s = fmaf(gl[k], Wco[k * C + c], s);
        gw[b * C + c] = s;
    }
}

// ------------------------------------------------ k_prep_w
__global__ __launch_bounds__(128) void k_prep_w(const float* __restrict__ Win,
                                                const float* __restrict__ Wci,
                                                const float* __restrict__ Wproj,
                                                const float* __restrict__ Wout,
                                                const float* __restrict__ w2,
                                                const float* __restrict__ b2,
                                                const float* __restrict__ wds,
                                                const float* __restrict__ wcd,
                                                ushort_t* __restrict__ Wio,
                                                ushort_t* __restrict__ Wcat,
                                                float* __restrict__ bp,
                                                float* __restrict__ kwS,
                                                float* __restrict__ kw1,
                                                float* __restrict__ kd0,
                                                float* __restrict__ kd1,
                                                float* __restrict__ kd2) {
    int o = blockIdx.x, c = threadIdx.x;
    __shared__ float pr[C];
    pr[c] = Wproj[o * C + c];
    __syncthreads();
    Wio[o * C + c] = f2bf(Win[o * C + c]);
    Wio[(C + o) * C + c] = f2bf(Wci[o * C + c]);
    float s = 0.f;
    for (int k = 0; k < C; k++) s = fmaf(pr[k], Wout[k * C + c], s);
    Wcat[o * 288 + c] = f2bf(s);
    Wcat[o * 288 + 128 + c] = f2bf(pr[c]);
    if (c < MID) {
        float s2 = 0.f;
        for (int k = 0; k < C; k++) s2 = fmaf(pr[k], w2[k * MID + c], s2);
        Wcat[o * 288 + 256 + c] = f2bf(s2);
    }
    if (c == 0) {
        float s3 = 0.f;
        for (int k = 0; k < C; k++) s3 = fmaf(pr[k], b2[k], s3);
        bp[o] = s3;
    }
    if (o == 0) {
        kwS[c] = 0.25f * (wds[3 * c] + wds[3 * c + 2]);
        kw1[c] = wds[3 * c + 1];
        kd0[c] = wcd[3 * c];
        kd1[c] = wcd[3 * c + 1];
        kd2[c] = wcd[3 * c + 2];
    }
}

// ------------------------------------------------ k_gemm1: tu[l][0:256] = [Win;Wci] @ x  (MFMA)
__global__ __launch_bounds__(512, 1) void k_gemm1(const ushort_t* __restrict__ xb,
                                                  const ushort_t* __restrict__ Wio,
                                                  ushort_t* __restrict__ tu) {
    __shared__ ushort_t wl[128 * 136];
    const int tid = threadIdx.x;
    const int bid = blockIdx.x;               // 8 b * 2 ms * 128 lt
    const int b = bid >> 8;
    const int ms = (bid >> 7) & 1;
    const int lt = bid & 127;
    {
        int row = tid >> 2, qq = tid & 3;
        const uint4* s4 = (const uint4*)(Wio + (ms * C + row) * C + qq * 32);
        uint4* d4 = (uint4*)(wl + row * 136 + qq * 32);
        d4[0] = s4[0]; d4[1] = s4[1]; d4[2] = s4[2]; d4[3] = s4[3];
    }
    __syncthreads();
    const int wave = tid >> 6, lane = tid & 63;
    const int l0 = lt * 128 + wave * 16;
    const int n = lane & 15, q = lane >> 4;
    const ushort_t* brow = xb + ((size_t)(b * L + l0 + n)) * C + q * 8;
    s8v bfrag[4];
#pragma unroll
    for (int ks = 0; ks < 4; ks++) bfrag[ks] = *(const s8v*)(brow + ks * 32);
    f4v acc[8];
#pragma unroll
    for (int i = 0; i < 8; i++) acc[i] = (f4v){0.f, 0.f, 0.f, 0.f};
#pragma unroll
    for (int ks = 0; ks < 4; ks++) {
#pragma unroll
        for (int mt = 0; mt < 8; mt++) {
            s8v af = *(const s8v*)(wl + (mt * 16 + n) * 136 + ks * 32 + q * 8);
            acc[mt] = __builtin_amdgcn_mfma_f32_16x16x32_bf16(af, bfrag[ks], acc[mt], 0, 0, 0);
        }
    }
    ushort_t* orow = tu + ((size_t)(b * L + l0 + n)) * 256 + ms * C + q * 4;
#pragma unroll
    for (int mt = 0; mt < 8; mt++) {
        union { ushort_t h[4]; uint2 q2; } u;
#pragma unroll
        for (int i = 0; i < 4; i++) u.h[i] = f2bf(acc[mt][i]);
        *(uint2*)(orow + mt * 16) = u.q2;
    }
}

// ------------------------------------------------ k_mid: stencils + silu -> Kbuf[l][288]
__global__ __launch_bounds__(256) void k_mid(const ushort_t* __restrict__ tu,
                                             const ushort_t* __restrict__ xb,
                                             const float* __restrict__ kwS,
                                             const float* __restrict__ kw1,
                                             const float* __restrict__ kd0,
                                             const float* __restrict__ kd1,
                                             const float* __restrict__ kd2,
                                             const float* __restrict__ gw,
                                             const float* __restrict__ a,
                                             const float* __restrict__ b1,
                                             const float* __restrict__ pdw,
                                             ushort_t* __restrict__ Kb) {
    const int tid = threadIdx.x;
    const int cc = tid & 15, p = tid >> 4;
    const int bid = blockIdx.x;
    const int b = bid >> 10;
    const int l = (bid & 1023) * 16 + p;
    const int y = l >> 7, xg = l & 127;
    const int c0 = cc * 8;
    const size_t rb = (size_t)b * L;

    const int rL = (l > 0) ? (l - 1) : -1;
    const int rR = (l < L - 1) ? (l + 1) : -1;
    const int rU = (y > 0) ? (l - 128) : ((xg > 0) ? (16256 + xg - 1) : -1);
    const int rD = (y < 127) ? (l + 128) : ((xg < 127) ? (xg + 1) : -1);
    const int sL = (xg > 0) ? (l - 1) : (l + 1);
    const int sR = (xg < 127) ? (l + 1) : (l - 1);
    const int sU = (y > 0) ? (l - 128) : (l + 128);
    const int sD = (y < 127) ? (l + 128) : (l - 128);

    float tC[8], tLe[8], tRi[8], tUp[8], tDo[8];
    load8(tu + (rb + l) * 256 + c0, tC);
    if (rL >= 0) load8(tu + (rb + rL) * 256 + c0, tLe); else zero8(tLe);
    if (rR >= 0) load8(tu + (rb + rR) * 256 + c0, tRi); else zero8(tRi);
    if (rU >= 0) load8(tu + (rb + rU) * 256 + c0, tUp); else zero8(tUp);
    if (rD >= 0) load8(tu + (rb + rD) * 256 + c0, tDo); else zero8(tDo);

    float uC[8], uL8[8], uR8[8];
    load8(tu + (rb + l) * 256 + 128 + c0, uC);
    if (rL >= 0) load8(tu + (rb + rL) * 256 + 128 + c0, uL8); else zero8(uL8);
    if (rR >= 0) load8(tu + (rb + rR) * 256 + 128 + c0, uR8); else zero8(uR8);

    float xC[8], xL8[8], xR8[8], xU8[8], xD8[8];
    load8(xb + (rb + l) * C + c0, xC);
    load8(xb + (rb + sL) * C + c0, xL8);
    load8(xb + (rb + sR) * C + c0, xR8);
    load8(xb + (rb + sU) * C + c0, xU8);
    load8(xb + (rb + sD) * C + c0, xD8);

    float kS[8], k1[8], d0[8], d1[8], d2[8], gv[8];
    ld8f(kwS + c0, kS); ld8f(kw1 + c0, k1);
    ld8f(kd0 + c0, d0); ld8f(kd1 + c0, d1); ld8f(kd2 + c0, d2);
    ld8f(gw + b * C + c0, gv);
    const float dwt = pdw[0] * 0.25f;

    float ct[8], yd[8];
    float s1 = 0.f;
#pragma unroll
    for (int j = 0; j < 8; j++) {
        ct[j] = kS[j] * ((tLe[j] + tRi[j]) + (tUp[j] + tDo[j])) + k1[j] * tC[j];
        float vv = d0[j] * uL8[j] + d1[j] * uC[j] + d2[j] * uR8[j];
        s1 = fmaf(gv[j], vv, s1);
        float cen = xC[j];
        float d = fabsf(cen - xL8[j]) + fabsf(cen - xR8[j]) +
                  fabsf(cen - xU8[j]) + fabsf(cen - xD8[j]);
        yd[j] = fmaf(dwt, d, cen);
    }
    s1 += __shfl_xor(s1, 1);
    s1 += __shfl_xor(s1, 2);
    s1 += __shfl_xor(s1, 4);
    s1 += __shfl_xor(s1, 8);

    ushort_t* kr = Kb + (rb + l) * 288;
    store8(kr + c0, ct);
    store8(kr + 128 + c0, yd);
    if (cc < 4) {
        float av[8], bv[8], sv[8];
        ld8f(a + b * MID + cc * 8, av);
        ld8f(b1 + cc * 8, bv);
#pragma unroll
        for (int j = 0; j < 8; j++) {
            float pre = fmaf(av[j], s1, bv[j]);
            sv[j] = pre / (1.f + __expf(-pre));
        }
        store8(kr + 256 + cc * 8, sv);
    }
}

// ------------------------------------------------ k_gemm2: ob(bf16) = Wcat @ Kbuf + bp, + BN partial stats
__global__ __launch_bounds__(512, 1) void k_gemm2(const ushort_t* __restrict__ Kb,
                                                  const ushort_t* __restrict__ Wcat,
                                                  const float* __restrict__ bp,
                                                  ushort_t* __restrict__ ob,
                                                  float* __restrict__ stats_p) {
    __shared__ ushort_t wl[64 * 296];
    __shared__ float rs_[8][64];
    __shared__ float rq_[8][64];
    const int tid = threadIdx.x;
    const int bid = blockIdx.x;               // 8 b * 2 ms * 128 lt
    const int b = bid >> 8;
    const int ms = (bid >> 7) & 1;
    const int lt = bid & 127;
    for (int i = 0; i < 5; i++) {
        int idx = tid + i * 512;              // uint4 index, total 2304
        if (idx < 2304) {
            int row = idx / 36, col = idx - row * 36;
            *(uint4*)(wl + row * 296 + col * 8) =
                *(const uint4*)(Wcat + (ms * 64 + row) * 288 + col * 8);
        }
    }
    __syncthreads();
    const int wave = tid >> 6, lane = tid & 63;
    const int l0 = lt * 128 + wave * 16;
    const int n = lane & 15, q = lane >> 4;
    const ushort_t* brow = Kb + ((size_t)(b * L + l0 + n)) * 288 + q * 8;
    f4v acc[4];
#pragma unroll
    for (int i = 0; i < 4; i++) acc[i] = (f4v){0.f, 0.f, 0.f, 0.f};
#pragma unroll
    for (int ks = 0; ks < 9; ks++) {
        s8v bf_ = *(const s8v*)(brow + ks * 32);
#pragma unroll
        for (int mt = 0; mt < 4; mt++) {
            s8v af = *(const s8v*)(wl + (mt * 16 + n) * 296 + ks * 32 + q * 8);
            acc[mt] = __builtin_amdgcn_mfma_f32_16x16x32_bf16(af, bf_, acc[mt], 0, 0, 0);
        }
    }
#pragma unroll
    for (int mt = 0; mt < 4; mt++) {
        int o0 = ms * 64 + mt * 16 + q * 4;
        float4 bv = *(const float4*)(bp + o0);
        float ba[4] = {bv.x, bv.y, bv.z, bv.w};
#pragma unroll
        for (int i = 0; i < 4; i++) {
            float v = acc[mt][i] + ba[i];
            ob[((size_t)(b * C + o0 + i)) * L + l0 + n] = f2bf(v);
            float s = v, sq = v * v;
            s += __shfl_xor(s, 1); s += __shfl_xor(s, 2);
            s += __shfl_xor(s, 4); s += __shfl_xor(s, 8);
            sq += __shfl_xor(sq, 1); sq += __shfl_xor(sq, 2);
            sq += __shfl_xor(sq, 4); sq += __shfl_xor(sq, 8);
            if (n == 0) {
                int ol = mt * 16 + q * 4 + i;
                rs_[wave][ol] = s;
                rq_[wave][ol] = sq;
            }
        }
    }
    __syncthreads();
    if (tid < 64) {
        float s = 0.f, sq = 0.f;
#pragma unroll
        for (int w = 0; w < 8; w++) { s += rs_[w][tid]; sq += rq_[w][tid]; }
        stats_p[(size_t)bid * 128 + tid] = s;
        stats_p[(size_t)bid * 128 + 64 + tid] = sq;
    }
}

// ------------------------------------------------ k_bnred: reduce stats_p -> stats[256]
__global__ __launch_bounds__(256) void k_bnred(const float* __restrict__ stats_p,
                                               float* __restrict__ stats) {
    const int j = blockIdx.x;       // 256: stat*128 + o
    const int stat = j >> 7, o = j & 127;
    const int ms = o >> 6, ol = o & 63;
    const int tid = threadIdx.x;
    float s = 0.f;
    for (int idx = tid; idx < 1024; idx += 256) {
        int b = idx >> 7, lt = idx & 127;
        int bid = b * 256 + ms * 128 + lt;
        s += stats_p[(size_t)bid * 128 + stat * 64 + ol];
    }
    __shared__ float red[256];
    red[tid] = s;
    __syncthreads();
    for (int w = 128; w > 0; w >>= 1) {
        if (tid < w) red[tid] += red[tid + w];
        __syncthreads();
    }
    if (tid == 0) stats[stat * 128 + o] = red[0];
}

// ------------------------------------------------ BN finalize + apply
__global__ void k_bnfin(const float* __restrict__ stats, const float* __restrict__ gamma,
                        const float* __restrict__ beta, float* __restrict__ scsh) {
    int o = threadIdx.x;
    float n = (float)NBL;
    float mu = stats[o] / n;
    float var = stats[C + o] / n - mu * mu;
    float sc = gamma[o] * rsqrtf(var + 1e-5f);
    scsh[o] = sc;
    scsh[C + o] = fmaf(-mu, sc, beta[o]);
}

__global__ __launch_bounds__(256) void k_bnapply(const ushort_t* __restrict__ ob,
                                                 float* __restrict__ outp,
                                                 const float* __restrict__ scsh) {
    const int bid = blockIdx.x;       // 2048
    const int bo = bid >> 1;
    const int half = bid & 1;
    const int o = bo & (C - 1);
    const float sc = scsh[o], sh = scsh[C + o];
    const ushort_t* src = ob + (size_t)bo * L + half * (L / 2);
    float* dst = outp + (size_t)bo * L + half * (L / 2);
    for (int i = threadIdx.x; i < (L / 2) / 8; i += 256) {
        float f[8];
        load8(src + i * 8, f);
        float4 v0, v1;
        v0.x = fmaf(f[0], sc, sh); v0.y = fmaf(f[1], sc, sh);
        v0.z = fmaf(f[2], sc, sh); v0.w = fmaf(f[3], sc, sh);
        v1.x = fmaf(f[4], sc, sh); v1.y = fmaf(f[5], sc, sh);
        v1.z = fmaf(f[6], sc, sh); v1.w = fmaf(f[7], sc, sh);
        *(float4*)(dst + i * 8) = v0;
        *(float4*)(dst + i * 8 + 4) = v1;
    }
}

// ------------------------------------------------ launch
extern "C" void kernel_launch(void* const* d_in, const int* in_sizes, int n_in,
                              void* d_out, int out_size, void* d_ws, size_t ws_size,
                              hipStream_t stream) {
    const float* x = (const float*)d_in[0];
    const float* Win = (const float*)d_in[1];
    const float* wds = (const float*)d_in[2];
    const float* Wout = (const float*)d_in[3];
    const float* Wci = (const float*)d_in[4];
    const float* wcd = (const float*)d_in[5];
    const float* Wco = (const float*)d_in[6];
    const float* w1 = (const float*)d_in[7];
    const float* b1 = (const float*)d_in[8];
    const float* w2 = (const float*)d_in[9];
    const float* b2 = (const float*)d_in[10];
    const float* pdw = (const float*)d_in[11];
    const float* gamma = (const float*)d_in[12];
    const float* beta = (const float*)d_in[13];
    const float* Wproj = (const float*)d_in[14];

    char* wsb = (char*)d_ws;
    ushort_t* xb = (ushort_t*)wsb;                       // 33,554,432 B (dead after k_mid)
    ushort_t* ob = (ushort_t*)wsb;                       // aliases xb — written by k_gemm2
    ushort_t* tu = (ushort_t*)(wsb + 33554432);          // 67,108,864 B
    ushort_t* Kb = (ushort_t*)(wsb + 100663296);         // 75,497,472 B
    char* S = wsb + 176160768;
    float* gap  = (float*)(S + 0);        // 1024 fl
    float* stats= (float*)(S + 4096);     // 256 fl
    float* scsh = (float*)(S + 5120);     // 256 fl
    float* a    = (float*)(S + 6144);     // 256 fl
    float* gw   = (float*)(S + 7168);     // 1024 fl
    float* bp   = (float*)(S + 11264);    // 128 fl
    float* kwS  = (float*)(S + 11776);
    float* kw1  = (float*)(S + 12288);
    float* kd0  = (float*)(S + 12800);
    float* kd1  = (float*)(S + 13312);
    float* kd2  = (float*)(S + 13824);
    ushort_t* Wio  = (ushort_t*)(S + 14336);   // 65,536 B
    ushort_t* Wcat = (ushort_t*)(S + 79872);   // 73,728 B
    float* stats_p = (float*)(S + 155648);     // 2048*128 fl = 1,048,576 B
    float* outp = (float*)d_out;

    hipMemsetAsync(S, 0, 4096, stream);  // gap only (stats written by k_bnred)
    k_cvt<<<2048, 256, 0, stream>>>(x, xb, gap);
    k_prep_b<<<8, 128, 0, stream>>>(gap, w1, Wco, a, gw);
    k_prep_w<<<128, 128, 0, stream>>>(Win, Wci, Wproj, Wout, w2, b2, wds, wcd,
                                      Wio, Wcat, bp, kwS, kw1, kd0, kd1, kd2);
    k_gemm1<<<2048, 512, 0, stream>>>(xb, Wio, tu);
    k_mid<<<8192, 256, 0, stream>>>(tu, xb, kwS, kw1, kd0, kd1, kd2, gw, a, b1, pdw, Kb);
    k_gemm2<<<2048, 512, 0, stream>>>(Kb, Wcat, bp, ob, stats_p);
    k_bnred<<<256, 256, 0, stream>>>(stats_p, stats);
    k_bnfin<<<1, 128, 0, stream>>>(stats, gamma, beta, scsh);
    k_bnapply<<<2048, 256, 0, stream>>>(ob, outp, scsh);
}